// Round 1
// baseline (445.314 us; speedup 1.0000x reference)
//
#include <hip/hip_runtime.h>
#include <math.h>

#define N_NODES 50000
#define N_EDGES 600000
#define DH 128
#define BATCH 16
#define SEQ 512
#define NROWS (BATCH*SEQ)   // 8192

// ---- workspace layout (float offsets) ----
// xw region (6.4M floats) is reused for X/Kp/Vp/O1 after the GAT scatter
#define OFF_X      0L
#define OFF_KP     1048576L
#define OFF_VP     2097152L
#define OFF_O1     3145728L
#define OFF_XW     0L
#define OFF_XOUT   6400000L
#define OFF_AS     12800000L
#define OFF_AD     12850000L
#define OFF_DEN    12900000L
#define OFF_MASK   12950000L
#define OFF_WC     13000000L
#define OFF_BC     13016384L
#define OFF_QP     13016512L
#define OFF_HB     13016896L
#define OFF_VPOD   13018944L

// ---------------- prep: Wc = lin_W @ gat_W, bc = lin_b @ gat_W, qp for mabs 0/2/4 ----------------
__global__ __launch_bounds__(256) void prep_kernel(
    const float* __restrict__ lin_W, const float* __restrict__ lin_b,
    const float* __restrict__ gat_W,
    const float* __restrict__ mab_Wq, const float* __restrict__ mab_bq,
    const float* __restrict__ isab_I, const float* __restrict__ pma_S,
    float* __restrict__ Wc, float* __restrict__ bc, float* __restrict__ qp)
{
    int t = blockIdx.x * 256 + threadIdx.x;
    if (t < 16384) {
        int i = t >> 7, j = t & 127;
        float s = 0.f;
        for (int k = 0; k < 128; ++k) s += lin_W[i*128 + k] * gat_W[k*128 + j];
        Wc[t] = s;
    } else if (t < 16512) {
        int j = t - 16384;
        float s = 0.f;
        for (int k = 0; k < 128; ++k) s += lin_b[k] * gat_W[k*128 + j];
        bc[j] = s;
    } else if (t < 16896) {
        int u = t - 16512;
        int m = u >> 7, c = u & 127;
        int mi = m * 2;   // mab index 0, 2, 4
        const float* vec = (m == 0) ? isab_I : (m == 1 ? isab_I + 128 : pma_S);
        float s = mab_bq[mi*128 + c];
        for (int k = 0; k < 128; ++k) s += vec[k] * mab_Wq[mi*16384 + k*128 + c];
        qp[u] = s;
    }
}

// ---------------- generic row-GEMM: out = X(rows x 128) @ W(128x128) + b, 16 rows/block ----------
// EPI 0: out1 = acc + b1
// EPI 1: dual: out1 = acc1 + b1 ; out2 = acc2 + b2
// EPI 2: out1 = acc + b1 + extra[batch(row)*128 + c]   (batch = row >> 9)
// EPI 3: out1 = Xin[r][c] + relu(acc + b1)
template<int EPI>
__global__ __launch_bounds__(256) void gemm128_kernel(
    const float* __restrict__ Xin,
    const float* __restrict__ W1, const float* __restrict__ b1,
    const float* __restrict__ W2, const float* __restrict__ b2,
    const float* __restrict__ extra,
    float* __restrict__ out1, float* __restrict__ out2)
{
    __shared__ float Xs[16][128];
    int t = threadIdx.x;
    long row0 = (long)blockIdx.x * 16;
    #pragma unroll
    for (int i = 0; i < 8; ++i) {
        int idx = i*256 + t;
        int r = idx >> 7, k = idx & 127;
        Xs[r][k] = Xin[(row0 + r)*128 + k];
    }
    __syncthreads();
    int c  = t & 127;
    int hh = t >> 7;               // 0/1 -> rows hh*8 .. hh*8+7
    float acc1[8], acc2[8];
    #pragma unroll
    for (int r = 0; r < 8; ++r) { acc1[r] = 0.f; acc2[r] = 0.f; }
    for (int k4 = 0; k4 < 128; k4 += 4) {
        float xv[8][4];
        #pragma unroll
        for (int r = 0; r < 8; ++r) {
            float4 tmp = *(const float4*)&Xs[hh*8 + r][k4];
            xv[r][0] = tmp.x; xv[r][1] = tmp.y; xv[r][2] = tmp.z; xv[r][3] = tmp.w;
        }
        #pragma unroll
        for (int kk = 0; kk < 4; ++kk) {
            float w1 = W1[(k4 + kk)*128 + c];
            float w2 = (EPI == 1) ? W2[(k4 + kk)*128 + c] : 0.f;
            #pragma unroll
            for (int r = 0; r < 8; ++r) {
                acc1[r] += xv[r][kk] * w1;
                if (EPI == 1) acc2[r] += xv[r][kk] * w2;
            }
        }
    }
    float bb  = b1[c];
    float bb2 = (EPI == 1) ? b2[c] : 0.f;
    if (EPI == 2) bb += extra[(row0 >> 9)*128 + c];
    #pragma unroll
    for (int r = 0; r < 8; ++r) {
        long row = row0 + hh*8 + r;
        float v = acc1[r] + bb;
        if (EPI == 3) v = Xs[hh*8 + r][c] + fmaxf(acc1[r] + bb, 0.f);
        out1[row*128 + c] = v;
        if (EPI == 1) out2[row*128 + c] = acc2[r] + bb2;
    }
}

// ---------------- per-node attention scalars a_s, a_d ----------------
__global__ __launch_bounds__(256) void avec_kernel(
    const float* __restrict__ xw, const float* __restrict__ att_src,
    const float* __restrict__ att_dst, float* __restrict__ a_s, float* __restrict__ a_d)
{
    int w = threadIdx.x >> 6, lane = threadIdx.x & 63;
    long row = (long)blockIdx.x * 4 + w;
    const float* xr = xw + row*128 + lane*2;
    float x0 = xr[0], x1 = xr[1];
    float s = x0*att_src[lane*2] + x1*att_src[lane*2 + 1];
    float d = x0*att_dst[lane*2] + x1*att_dst[lane*2 + 1];
    #pragma unroll
    for (int off = 32; off > 0; off >>= 1) {
        s += __shfl_down(s, off);
        d += __shfl_down(d, off);
    }
    if (lane == 0) { a_s[row] = s; a_d[row] = d; }
}

// ---------------- mark needed destination nodes ----------------
__global__ void maskset_kernel(const int* __restrict__ node_ids, int* __restrict__ mask)
{
    int i = blockIdx.x*256 + threadIdx.x;
    if (i < NROWS) mask[node_ids[i]] = 1;
}

// ---------------- GAT softmax denominator (max-shift skipped: logits are O(1)) -----------------
__global__ __launch_bounds__(256) void den_kernel(
    const int* __restrict__ edge_idx, const int* __restrict__ mask,
    const float* __restrict__ a_s, const float* __restrict__ a_d,
    float* __restrict__ den)
{
    int i = blockIdx.x*256 + threadIdx.x;
    if (i >= N_EDGES + N_NODES) return;
    int s, dd;
    if (i < N_EDGES) { s = edge_idx[i]; dd = edge_idx[N_EDGES + i]; }
    else             { s = dd = i - N_EDGES; }
    if (!mask[dd]) return;
    float e = a_s[s] + a_d[dd];
    e = (e > 0.f) ? e : 0.2f * e;
    atomicAdd(&den[dd], __expf(e));
}

// ---------------- GAT weighted scatter-add, one wave per edge ----------------
__global__ __launch_bounds__(256) void scatter_kernel(
    const int* __restrict__ edge_idx, const int* __restrict__ mask,
    const float* __restrict__ a_s, const float* __restrict__ a_d,
    const float* __restrict__ den, const float* __restrict__ xw,
    float* __restrict__ x_out)
{
    int item = blockIdx.x*4 + (threadIdx.x >> 6);
    int lane = threadIdx.x & 63;
    if (item >= N_EDGES + N_NODES) return;
    int s, dd;
    if (item < N_EDGES) { s = edge_idx[item]; dd = edge_idx[N_EDGES + item]; }
    else                { s = dd = item - N_EDGES; }
    if (!mask[dd]) return;
    float e = a_s[s] + a_d[dd];
    e = (e > 0.f) ? e : 0.2f * e;
    float coef = __expf(e) / den[dd];
    const float* xr = xw + (long)s*128 + lane*2;
    float v0 = xr[0] * coef, v1 = xr[1] * coef;
    float* o = x_out + (long)dd*128 + lane*2;
    atomicAdd(o,     v0);
    atomicAdd(o + 1, v1);
}

// ---------------- gather sampled node rows + bias ----------------
__global__ __launch_bounds__(256) void gather_kernel(
    const int* __restrict__ node_ids, const float* __restrict__ x_out,
    const float* __restrict__ gat_bias, float* __restrict__ X)
{
    int w = threadIdx.x >> 6, lane = threadIdx.x & 63;
    int j = blockIdx.x*4 + w;
    int id = node_ids[j];
    const float* xr = x_out + (long)id*128 + lane*2;
    float* o = X + (long)j*128 + lane*2;
    o[0] = xr[0] + gat_bias[lane*2];
    o[1] = xr[1] + gat_bias[lane*2 + 1];
}

// ---------------- 128x128 matvec with 512 threads (4-way split-K + LDS reduce) -----------------
// returns (for t<128) sum over k of xs[k]*W[k*128+t]; all 512 threads must call.
__device__ __forceinline__ float matvec_qs(
    const float* __restrict__ W, const float* xs, float (*red)[128], int t)
{
    int c = t & 127, q = t >> 7;
    float acc = 0.f;
    #pragma unroll
    for (int j = 0; j < 32; ++j) {
        int k = q*32 + j;
        acc += xs[k] * W[k*128 + c];
    }
    red[q][c] = acc;
    __syncthreads();
    float s = 0.f;
    if (t < 128) s = red[0][t] + red[1][t] + red[2][t] + red[3][t];
    __syncthreads();
    return s;
}

// ---------------- even MAB (q-len 1): softmax over 512 keys, H = O + relu(O@Wo+bo), vpod --------
__global__ __launch_bounds__(512) void attn_even_kernel(
    const float* __restrict__ Kp, const float* __restrict__ Vp,
    const float* __restrict__ qp,
    const float* __restrict__ Wo, const float* __restrict__ bo,
    const float* __restrict__ Wv1, const float* __restrict__ bv1,
    float* __restrict__ Hout, float* __restrict__ vpod)
{
    __shared__ float l_sm[4][512];
    __shared__ float red[4][128];
    __shared__ float red64[4][64];
    __shared__ float mx[4], dn[4];
    __shared__ float qs[128], Ovec[128], Hsm[128];
    int b = blockIdx.x, t = threadIdx.x;
    if (t < 128) qs[t] = qp[t];
    __syncthreads();
    const float scale = 0.088388347648318447f;  // 1/sqrt(128)
    {
        const float* kr = Kp + ((long)b*512 + t)*128;
        float l[4] = {0.f, 0.f, 0.f, 0.f};
        #pragma unroll
        for (int d4 = 0; d4 < 128; d4 += 4) {
            float4 kv = *(const float4*)&kr[d4];
            float4 qv = *(const float4*)&qs[d4];
            l[d4 >> 5] += kv.x*qv.x + kv.y*qv.y + kv.z*qv.z + kv.w*qv.w;
        }
        #pragma unroll
        for (int h = 0; h < 4; ++h) l_sm[h][t] = l[h] * scale;
    }
    __syncthreads();
    if (t < 256) {
        int h = t >> 6, i = t & 63;
        float m = -1e30f;
        #pragma unroll
        for (int j = 0; j < 8; ++j) m = fmaxf(m, l_sm[h][i + 64*j]);
        red64[h][i] = m;
    }
    __syncthreads();
    if (t < 4) {
        float m = -1e30f;
        for (int i = 0; i < 64; ++i) m = fmaxf(m, red64[t][i]);
        mx[t] = m;
    }
    __syncthreads();
    #pragma unroll
    for (int h = 0; h < 4; ++h) l_sm[h][t] = __expf(l_sm[h][t] - mx[h]);
    __syncthreads();
    if (t < 256) {
        int h = t >> 6, i = t & 63;
        float ssum = 0.f;
        #pragma unroll
        for (int j = 0; j < 8; ++j) ssum += l_sm[h][i + 64*j];
        red64[h][i] = ssum;
    }
    __syncthreads();
    if (t < 4) {
        float sm = 0.f;
        for (int i = 0; i < 64; ++i) sm += red64[t][i];
        dn[t] = 1.f / sm;
    }
    __syncthreads();
    {
        int c = t & 127, q = t >> 7, h = c >> 5;
        const float* vp = Vp + ((long)b*512 + q*128)*128 + c;
        float acc = 0.f;
        for (int k = 0; k < 128; ++k) acc += l_sm[h][q*128 + k] * vp[(long)k*128];
        red[q][c] = acc;
    }
    __syncthreads();
    if (t < 128) Ovec[t] = qs[t] + (red[0][t] + red[1][t] + red[2][t] + red[3][t]) * dn[t >> 5];
    __syncthreads();
    float mv = matvec_qs(Wo, Ovec, red, t);
    if (t < 128) {
        float hv = Ovec[t] + fmaxf(mv + bo[t], 0.f);
        Hsm[t] = hv;
        Hout[b*128 + t] = hv;
    }
    __syncthreads();
    float mv2 = matvec_qs(Wv1, Hsm, red, t);
    if (t < 128) vpod[b*128 + t] = mv2 + bv1[t];
}

// ---------------- PMA + SAB + SAB + dec + prototypes, fully fused (16 blocks) -------------------
__global__ __launch_bounds__(512) void attn_pma_kernel(
    const float* __restrict__ Kp, const float* __restrict__ Vp,
    const float* __restrict__ qp,
    const float* __restrict__ mab_Wq, const float* __restrict__ mab_bq,
    const float* __restrict__ mab_Wv, const float* __restrict__ mab_bv,
    const float* __restrict__ mab_Wo, const float* __restrict__ mab_bo,
    const float* __restrict__ dec_W, const float* __restrict__ dec_b,
    const float* __restrict__ protos, float* __restrict__ out)
{
    __shared__ float l_sm[4][512];
    __shared__ float red[4][128];
    __shared__ float red64[4][64];
    __shared__ float mx[4], dn[4];
    __shared__ float qs[128], Ovec[128], S1[128], S2[128];
    int b = blockIdx.x, t = threadIdx.x;
    if (t < 128) qs[t] = qp[t];
    __syncthreads();
    const float scale = 0.088388347648318447f;
    {
        const float* kr = Kp + ((long)b*512 + t)*128;
        float l[4] = {0.f, 0.f, 0.f, 0.f};
        #pragma unroll
        for (int d4 = 0; d4 < 128; d4 += 4) {
            float4 kv = *(const float4*)&kr[d4];
            float4 qv = *(const float4*)&qs[d4];
            l[d4 >> 5] += kv.x*qv.x + kv.y*qv.y + kv.z*qv.z + kv.w*qv.w;
        }
        #pragma unroll
        for (int h = 0; h < 4; ++h) l_sm[h][t] = l[h] * scale;
    }
    __syncthreads();
    if (t < 256) {
        int h = t >> 6, i = t & 63;
        float m = -1e30f;
        #pragma unroll
        for (int j = 0; j < 8; ++j) m = fmaxf(m, l_sm[h][i + 64*j]);
        red64[h][i] = m;
    }
    __syncthreads();
    if (t < 4) {
        float m = -1e30f;
        for (int i = 0; i < 64; ++i) m = fmaxf(m, red64[t][i]);
        mx[t] = m;
    }
    __syncthreads();
    #pragma unroll
    for (int h = 0; h < 4; ++h) l_sm[h][t] = __expf(l_sm[h][t] - mx[h]);
    __syncthreads();
    if (t < 256) {
        int h = t >> 6, i = t & 63;
        float ssum = 0.f;
        #pragma unroll
        for (int j = 0; j < 8; ++j) ssum += l_sm[h][i + 64*j];
        red64[h][i] = ssum;
    }
    __syncthreads();
    if (t < 4) {
        float sm = 0.f;
        for (int i = 0; i < 64; ++i) sm += red64[t][i];
        dn[t] = 1.f / sm;
    }
    __syncthreads();
    {
        int c = t & 127, q = t >> 7, h = c >> 5;
        const float* vp = Vp + ((long)b*512 + q*128)*128 + c;
        float acc = 0.f;
        for (int k = 0; k < 128; ++k) acc += l_sm[h][q*128 + k] * vp[(long)k*128];
        red[q][c] = acc;
    }
    __syncthreads();
    if (t < 128) Ovec[t] = qs[t] + (red[0][t] + red[1][t] + red[2][t] + red[3][t]) * dn[t >> 5];
    __syncthreads();
    // X5 = O + relu(O@Wo4 + bo4)
    float mv = matvec_qs(mab_Wo + 4*16384, Ovec, red, t);
    if (t < 128) S1[t] = Ovec[t] + fmaxf(mv + mab_bo[4*128 + t], 0.f);
    __syncthreads();
    // SAB (mab5): O5 = Qp5 + Vp5 ; X6 = O5 + relu(O5@Wo5 + bo5)
    float q5 = matvec_qs(mab_Wq + 5*16384, S1, red, t);
    float v5 = matvec_qs(mab_Wv + 5*16384, S1, red, t);
    if (t < 128) S2[t] = q5 + mab_bq[5*128 + t] + v5 + mab_bv[5*128 + t];
    __syncthreads();
    float m5 = matvec_qs(mab_Wo + 5*16384, S2, red, t);
    if (t < 128) S1[t] = S2[t] + fmaxf(m5 + mab_bo[5*128 + t], 0.f);
    __syncthreads();
    // SAB (mab6)
    float q6 = matvec_qs(mab_Wq + 6*16384, S1, red, t);
    float v6 = matvec_qs(mab_Wv + 6*16384, S1, red, t);
    if (t < 128) S2[t] = q6 + mab_bq[6*128 + t] + v6 + mab_bv[6*128 + t];
    __syncthreads();
    float m6 = matvec_qs(mab_Wo + 6*16384, S2, red, t);
    if (t < 128) S1[t] = S2[t] + fmaxf(m6 + mab_bo[6*128 + t], 0.f);
    __syncthreads();
    // dec linear
    float y = matvec_qs(dec_W, S1, red, t);
    if (t < 128) out[b*768 + t] = y + dec_b[t];
    // prototypes -> rows 1..5
    {
        int p = t >> 7, c = t & 127;
        out[b*768 + (1 + p)*128 + c] = protos[p*128 + c];
        if (t < 128) out[b*768 + 640 + t] = protos[512 + t];
    }
}

extern "C" void kernel_launch(void* const* d_in, const int* in_sizes, int n_in,
                              void* d_out, int out_size, void* d_ws, size_t ws_size,
                              hipStream_t stream)
{
    (void)in_sizes; (void)n_in; (void)out_size; (void)ws_size;
    const int*   node_ids  = (const int*)d_in[0];
    const int*   edge_idx  = (const int*)d_in[1];
    const float* node_embed= (const float*)d_in[3];
    const float* lin_W     = (const float*)d_in[4];
    const float* lin_b     = (const float*)d_in[5];
    const float* gat_W     = (const float*)d_in[6];
    const float* att_src   = (const float*)d_in[7];
    const float* att_dst   = (const float*)d_in[8];
    const float* gat_bias  = (const float*)d_in[9];
    const float* mab_Wq    = (const float*)d_in[10];
    const float* mab_bq    = (const float*)d_in[11];
    const float* mab_Wk    = (const float*)d_in[12];
    const float* mab_bk    = (const float*)d_in[13];
    const float* mab_Wv    = (const float*)d_in[14];
    const float* mab_bv    = (const float*)d_in[15];
    const float* mab_Wo    = (const float*)d_in[16];
    const float* mab_bo    = (const float*)d_in[17];
    const float* isab_I    = (const float*)d_in[18];
    const float* pma_S     = (const float*)d_in[19];
    const float* dec_W     = (const float*)d_in[20];
    const float* dec_b     = (const float*)d_in[21];
    const float* protos    = (const float*)d_in[22];

    float* ws   = (float*)d_ws;
    float* X    = ws + OFF_X;
    float* Kp   = ws + OFF_KP;
    float* Vp   = ws + OFF_VP;
    float* O1   = ws + OFF_O1;
    float* xw   = ws + OFF_XW;
    float* x_out= ws + OFF_XOUT;
    float* a_s  = ws + OFF_AS;
    float* a_d  = ws + OFF_AD;
    float* den  = ws + OFF_DEN;
    int*   mask = (int*)(ws + OFF_MASK);
    float* Wc   = ws + OFF_WC;
    float* bc   = ws + OFF_BC;
    float* qp   = ws + OFF_QP;
    float* Hb   = ws + OFF_HB;
    float* vpod = ws + OFF_VPOD;
    float* out  = (float*)d_out;

    hipMemsetAsync(den,   0, N_NODES*sizeof(float), stream);
    hipMemsetAsync(mask,  0, N_NODES*sizeof(int),   stream);
    hipMemsetAsync(x_out, 0, (size_t)N_NODES*128*sizeof(float), stream);

    prep_kernel<<<66, 256, 0, stream>>>(lin_W, lin_b, gat_W, mab_Wq, mab_bq, isab_I, pma_S,
                                        Wc, bc, qp);
    // xw = node_embed[:N] @ (lin_W @ gat_W) + lin_b @ gat_W
    gemm128_kernel<0><<<N_NODES/16, 256, 0, stream>>>(node_embed, Wc, bc,
                                                      nullptr, nullptr, nullptr, xw, nullptr);
    avec_kernel<<<N_NODES/4, 256, 0, stream>>>(xw, att_src, att_dst, a_s, a_d);
    maskset_kernel<<<(NROWS + 255)/256, 256, 0, stream>>>(node_ids, mask);
    den_kernel<<<(N_EDGES + N_NODES + 255)/256, 256, 0, stream>>>(edge_idx, mask, a_s, a_d, den);
    scatter_kernel<<<(N_EDGES + N_NODES)/4, 256, 0, stream>>>(edge_idx, mask, a_s, a_d, den,
                                                              xw, x_out);
    gather_kernel<<<NROWS/4, 256, 0, stream>>>(node_ids, x_out, gat_bias, X);

    for (int i = 0; i < 2; ++i) {
        int e = 2*i, o = 2*i + 1;
        gemm128_kernel<1><<<NROWS/16, 256, 0, stream>>>(X, mab_Wk + e*16384, mab_bk + e*128,
                                                        mab_Wv + e*16384, mab_bv + e*128,
                                                        nullptr, Kp, Vp);
        attn_even_kernel<<<16, 512, 0, stream>>>(Kp, Vp, qp + i*128,
                                                 mab_Wo + e*16384, mab_bo + e*128,
                                                 mab_Wv + o*16384, mab_bv + o*128,
                                                 Hb, vpod);
        gemm128_kernel<2><<<NROWS/16, 256, 0, stream>>>(X, mab_Wq + o*16384, mab_bq + o*128,
                                                        nullptr, nullptr, vpod, O1, nullptr);
        gemm128_kernel<3><<<NROWS/16, 256, 0, stream>>>(O1, mab_Wo + o*16384, mab_bo + o*128,
                                                        nullptr, nullptr, nullptr, X, nullptr);
    }
    gemm128_kernel<1><<<NROWS/16, 256, 0, stream>>>(X, mab_Wk + 4*16384, mab_bk + 4*128,
                                                    mab_Wv + 4*16384, mab_bv + 4*128,
                                                    nullptr, Kp, Vp);
    attn_pma_kernel<<<16, 512, 0, stream>>>(Kp, Vp, qp + 256,
                                            mab_Wq, mab_bq, mab_Wv, mab_bv, mab_Wo, mab_bo,
                                            dec_W, dec_b, protos, out);
}